// Round 18
// baseline (83.869 us; speedup 1.0000x reference)
//
#include <hip/hip_runtime.h>
#include <hip/hip_bf16.h>

// GAT fused forward loss.
// R18 = R17 (64.6us champion) + MEASUREMENT: k_mattn launched TWICE
// (idempotent: pure function of inputs, rewrites identical partials).
// T_mattn = total - 64.6. Budget model vs reality disagree 4x; 3 blind
// rounds produced ~1us. Measure before editing further.
// Structure: sampled rows (only h_all[idx_train] live), factored exp,
// MFMA j-amortization over 16 samples, Z via MFMA vs ones, grouped adj
// preload, sc-major block mapping, bf16 partials.

#define NN 8192
#define FTDIM 512
#define CDIM 64
#define NTRAIN 1024
#define LOG2E 1.44269504088896f

typedef __attribute__((ext_vector_type(8))) short short8;
typedef __attribute__((ext_vector_type(4))) float f32x4;
typedef __attribute__((ext_vector_type(4))) int i32x4;

static __device__ __forceinline__ unsigned short f2bf(float x) {
    return __bfloat16_as_ushort(__float2bfloat16(x));
}
static __device__ __forceinline__ float bf2f(unsigned short u) {
    return __uint_as_float((unsigned)u << 16);
}

// ---------------------------------------------------------------------------
// Kernel A (R14): Wh = feat @ W, W LDS-staged. Block = 4 waves; wave = 4 rows;
// 512 blocks. Two K-halves: stage W[half][256][64] (64KB), barrier, FMA.
// Epilogue: Vt2[jblk][c][e] = bf16(Wh[jblk*8+e][c]) + factored-exp tables.
// ---------------------------------------------------------------------------
__global__ __launch_bounds__(256) void k_wh(
    const float* __restrict__ feat, const float* __restrict__ W,
    const float* __restrict__ av, unsigned short* __restrict__ Vt2,
    float4* __restrict__ sQ, float* __restrict__ dE1, float* __restrict__ dE2)
{
    __shared__ float wlds[256 * CDIM];   // 64 KB

    const int tid  = threadIdx.x;
    const int lane = tid & 63;
    const int wv   = tid >> 6;
    const int gw   = blockIdx.x * 4 + wv;     // 0..2047
    const int row0 = gw * 4;
    const int c    = lane;

    float acc[4] = {0.f, 0.f, 0.f, 0.f};

#pragma unroll
    for (int half = 0; half < 2; ++half) {
        if (half) __syncthreads();
#pragma unroll
        for (int q = 0; q < 16; ++q) {
            const int idx = q * 256 + tid;
            *(f32x4*)&wlds[idx * 4] =
                *(const f32x4*)(W + half * (256 * CDIM) + idx * 4);
        }
        __syncthreads();

        const float* __restrict__ fb = feat + half * 256;
        for (int k = 0; k < 256; k += 4) {
            f32x4 f[4];
#pragma unroll
            for (int r = 0; r < 4; ++r)
                f[r] = *(const f32x4*)(fb + (size_t)(row0 + r) * FTDIM + k);
#pragma unroll
            for (int kk = 0; kk < 4; ++kk) {
                const float wval = wlds[(k + kk) * CDIM + c];
#pragma unroll
                for (int r = 0; r < 4; ++r)
                    acc[r] = fmaf(f[r][kk], wval, acc[r]);
            }
        }
    }

    ushort4 v4;
    v4.x = f2bf(acc[0]); v4.y = f2bf(acc[1]);
    v4.z = f2bf(acc[2]); v4.w = f2bf(acc[3]);
    *(ushort4*)(Vt2 + (size_t)(row0 >> 3) * 512 + c * 8 + (row0 & 7)) = v4;

    const float a1 = av[c], a2 = av[CDIM + c];
#pragma unroll
    for (int r = 0; r < 4; ++r) {
        float s_ = acc[r] * a1;
        float d_ = acc[r] * a2;
#pragma unroll
        for (int off = 32; off; off >>= 1) {
            s_ += __shfl_xor(s_, off);
            d_ += __shfl_xor(d_, off);
        }
        if (lane == 0) {
            const float sp = s_ * LOG2E, dp_ = d_ * LOG2E;
            sQ[row0 + r] = make_float4(__builtin_amdgcn_exp2f(sp),
                                       __builtin_amdgcn_exp2f(0.2f * sp),
                                       __builtin_amdgcn_exp2f(-sp), 0.f);
            dE1[row0 + r] = __builtin_amdgcn_exp2f(dp_);
            dE2[row0 + r] = __builtin_amdgcn_exp2f(0.2f * dp_);
        }
    }
}

// ---------------------------------------------------------------------------
// Kernel M (R17): wave = (layer l, sample-block sb, chunk sc), sc-major block
// mapping (4 waves share the Vt2/dE window). Grouped adj preload -> mbits.
// Main loop: 2-deep pipeline; p = bit ? (e1>th ? E1*e1 : E2*e2) : 0 -> bf16
// A-frag; 4 MFMAs + 1 vs ones = Z. Partials: numPart bf16, zPart f32.
// PURE function of inputs -> safe to launch twice (measurement).
// ---------------------------------------------------------------------------
struct TileS {
    f32x4 a0, a1, b0, b1;
    short8 v0, v1, v2, v3;
};

template<int SCL>
__global__ __launch_bounds__(256, 4) void k_mattn(
    const int* __restrict__ adj1, const int* __restrict__ adj2,
    const unsigned short* __restrict__ Vt2, const float4* __restrict__ sQ,
    const float* __restrict__ dE1, const float* __restrict__ dE2,
    const int* __restrict__ idxt,
    unsigned short* __restrict__ numPartB, float* __restrict__ zPart)
{
    constexpr int NT = (NN >> SCL) >> 5;
    const int lane = threadIdx.x & 63;
    const int w = (int)((blockIdx.x * blockDim.x + threadIdx.x) >> 6);
    const int l   = w >> (6 + SCL);
    const int rem = w & ((64 << SCL) - 1);
    const int sc  = rem >> 6;          // sc-major: block's 4 waves share sc
    const int sb  = rem & 63;

    const int r  = lane & 15;
    const int kg = lane >> 4;

    const int i = idxt[sb * 16 + r];
    const float4 sq = sQ[i];
    const float E1 = sq.x, E2 = sq.y, th = sq.z;

    const int j0 = sc * (NN >> SCL);
    const int* __restrict__ arow = (l ? adj2 : adj1) + (size_t)i * NN + j0 + kg * 8;
    const float* __restrict__ d1p = dE1 + j0 + kg * 8;
    const float* __restrict__ d2p = dE2 + j0 + kg * 8;
    const unsigned short* __restrict__ vbase =
        Vt2 + (((size_t)j0 >> 3) << 9) + ((size_t)kg << 9) + (r << 3);

    unsigned mbits[NT];
#pragma unroll
    for (int g = 0; g < NT; g += 4) {
        i32x4 gm0[4], gm1[4];
#pragma unroll
        for (int t = 0; t < 4; ++t) {
            gm0[t] = *(const i32x4*)(arow + (g + t) * 32);
            gm1[t] = *(const i32x4*)(arow + (g + t) * 32 + 4);
        }
#pragma unroll
        for (int t = 0; t < 4; ++t) {
            unsigned m = 0;
#pragma unroll
            for (int e = 0; e < 4; ++e) {
                m |= (gm0[t][e] != 0 ? 1u : 0u) << e;
                m |= (gm1[t][e] != 0 ? 1u : 0u) << (4 + e);
            }
            mbits[g + t] = m;
        }
    }

    short8 bOnes;
#pragma unroll
    for (int e = 0; e < 8; ++e) bOnes[e] = (short)0x3F80;   // bf16 1.0

    f32x4 acc0 = {0.f, 0.f, 0.f, 0.f};
    f32x4 acc1 = acc0, acc2 = acc0, acc3 = acc0, accz = acc0;

    TileS tA, tB;

#define LOADT(T, JT) do { const int _jr = (JT) * 32;                           \
    T.a0 = *(const f32x4*)(d1p + _jr);                                         \
    T.a1 = *(const f32x4*)(d1p + _jr + 4);                                     \
    T.b0 = *(const f32x4*)(d2p + _jr);                                         \
    T.b1 = *(const f32x4*)(d2p + _jr + 4);                                     \
    const unsigned short* _vp = vbase + ((size_t)(JT) << 11);                  \
    T.v0 = *(const short8*)(_vp);                                              \
    T.v1 = *(const short8*)(_vp + 128);                                        \
    T.v2 = *(const short8*)(_vp + 256);                                        \
    T.v3 = *(const short8*)(_vp + 384);                                        \
} while (0)

#define COMPT(T, JT) do {                                                      \
    const unsigned _mb = mbits[JT];                                            \
    short8 af;                                                                 \
    _Pragma("unroll")                                                          \
    for (int e = 0; e < 8; ++e) {                                              \
        const float e1 = (e < 4) ? T.a0[e & 3] : T.a1[e & 3];                  \
        const float e2 = (e < 4) ? T.b0[e & 3] : T.b1[e & 3];                  \
        const bool pos = e1 > th;                                              \
        float p = (pos ? e1 : e2) * (pos ? E1 : E2);                           \
        p = ((_mb >> e) & 1u) ? p : 0.f;                                       \
        af[e] = (short)f2bf(p);                                                \
    }                                                                          \
    acc0 = __builtin_amdgcn_mfma_f32_16x16x32_bf16(af, T.v0, acc0, 0, 0, 0);   \
    acc1 = __builtin_amdgcn_mfma_f32_16x16x32_bf16(af, T.v1, acc1, 0, 0, 0);   \
    acc2 = __builtin_amdgcn_mfma_f32_16x16x32_bf16(af, T.v2, acc2, 0, 0, 0);   \
    acc3 = __builtin_amdgcn_mfma_f32_16x16x32_bf16(af, T.v3, acc3, 0, 0, 0);   \
    accz = __builtin_amdgcn_mfma_f32_16x16x32_bf16(af, bOnes, accz, 0, 0, 0);  \
} while (0)

    LOADT(tA, 0);
#pragma unroll
    for (int jt = 0; jt < NT - 2; jt += 2) {
        LOADT(tB, jt + 1);
        COMPT(tA, jt);
        LOADT(tA, jt + 2);
        COMPT(tB, jt + 1);
    }
    LOADT(tB, NT - 1);
    COMPT(tA, NT - 2);
    COMPT(tB, NT - 1);
#undef LOADT
#undef COMPT

    constexpr int SC = 1 << SCL;
#pragma unroll
    for (int q = 0; q < 4; ++q) {
        const int ks = sb * 16 + kg * 4 + q;
        const size_t slot = ((size_t)ks * 2 + l) * SC + sc;
        unsigned short* op = numPartB + slot * CDIM + r;
        op[0]  = f2bf(acc0[q]);
        op[16] = f2bf(acc1[q]);
        op[32] = f2bf(acc2[q]);
        op[48] = f2bf(acc3[q]);
        if (r == 0) zPart[slot] = accz[q];
    }
}

// ---------------------------------------------------------------------------
// Kernel C: per-sample loss. One wave per sample k, lane = class.
// ---------------------------------------------------------------------------
__global__ __launch_bounds__(256) void k_loss(
    const unsigned short* __restrict__ numPartB, const float* __restrict__ zPart,
    const int* __restrict__ labels, const int* __restrict__ idxt,
    float* __restrict__ losses, const int scLog2)
{
    const int lane = threadIdx.x & 63;
    const int k = (int)((blockIdx.x * blockDim.x + threadIdx.x) >> 6);
    const int SC = 1 << scLog2;

    float logit = 0.f;
#pragma unroll
    for (int l = 0; l < 2; ++l) {
        const size_t base = ((size_t)k * 2 + l) * SC;
        float ns = 0.f;
#pragma unroll 16
        for (int s = 0; s < SC; ++s)
            ns += bf2f(numPartB[(base + s) * CDIM + lane]);
        float zs = (lane < SC) ? zPart[base + lane] : 0.f;
#pragma unroll
        for (int off = 32; off; off >>= 1) zs += __shfl_xor(zs, off);
        logit += fmaxf(ns / zs, 0.f);   // relu(elu(x)) == relu(x)
    }
    logit *= 0.5f;

    float m = logit;
#pragma unroll
    for (int off = 32; off; off >>= 1) m = fmaxf(m, __shfl_xor(m, off));
    float ex = __expf(logit - m);
    float sum = ex;
#pragma unroll
    for (int off = 32; off; off >>= 1) sum += __shfl_xor(sum, off);
    const float logp = logit - m - __logf(sum);

    const int y = labels[idxt[k]];
    const float t = __shfl(logp, y);
    if (lane == 0) losses[k] = -t;
}

// ---------------------------------------------------------------------------
// Kernel D: mean of 1024 per-sample losses -> d_out[0].
// ---------------------------------------------------------------------------
__global__ __launch_bounds__(256) void k_reduce(
    const float* __restrict__ losses, float* __restrict__ out)
{
    __shared__ float sbuf[4];
    const int tid = threadIdx.x;
    float v = losses[tid] + losses[tid + 256] + losses[tid + 512] + losses[tid + 768];
#pragma unroll
    for (int off = 32; off; off >>= 1) v += __shfl_xor(v, off);
    if ((tid & 63) == 0) sbuf[tid >> 6] = v;
    __syncthreads();
    if (tid == 0) out[0] = (sbuf[0] + sbuf[1] + sbuf[2] + sbuf[3]) * (1.f / 1024.f);
}

// ---------------------------------------------------------------------------
extern "C" void kernel_launch(void* const* d_in, const int* in_sizes, int n_in,
                              void* d_out, int out_size, void* d_ws, size_t ws_size,
                              hipStream_t stream)
{
    const float* feat   = (const float*)d_in[0];
    const float* W      = (const float*)d_in[1];
    const float* av     = (const float*)d_in[2];
    const int*   adj1   = (const int*)d_in[3];
    const int*   adj2   = (const int*)d_in[4];
    const int*   labels = (const int*)d_in[5];
    const int*   idxt   = (const int*)d_in[6];

    const size_t HEAD = (1u << 20) + (192u << 10);  // Vt2 1MB + sQ 128KB + dE1/2 64KB

    auto needed = [&](int scl) -> size_t {
        const size_t SC = (size_t)1 << scl;
        return HEAD + 2 * SC * NTRAIN * CDIM * sizeof(unsigned short)
                    + 2 * SC * NTRAIN * sizeof(float)
                    + NTRAIN * sizeof(float);
    };
    const int scLog2 = (ws_size >= needed(5)) ? 5 : 4;
    const int SC = 1 << scLog2;

    char* ws = (char*)d_ws;
    unsigned short* Vt2 = (unsigned short*)ws;                  // 1 MB
    float4* sQ  = (float4*)(ws + (1u << 20));                   // 128 KB
    float*  dE1 = (float*)(ws + (1u << 20) + (128u << 10));     // 32 KB
    float*  dE2 = (float*)(ws + (1u << 20) + (160u << 10));     // 32 KB
    unsigned short* numPartB = (unsigned short*)(ws + HEAD);
    float*  zPart  = (float*)((char*)numPartB
                              + 2ull * SC * NTRAIN * CDIM * sizeof(unsigned short));
    float*  losses = zPart + 2ull * SC * NTRAIN;

    hipLaunchKernelGGL(k_wh, dim3(512), dim3(256), 0, stream,
                       feat, W, av, Vt2, sQ, dE1, dE2);
    // MEASUREMENT: k_mattn twice (idempotent). T_mattn = total - 64.6us.
    if (scLog2 == 5) {
        hipLaunchKernelGGL((k_mattn<5>), dim3(32 * 32), dim3(256), 0, stream,
                           adj1, adj2, Vt2, sQ, dE1, dE2, idxt, numPartB, zPart);
        hipLaunchKernelGGL((k_mattn<5>), dim3(32 * 32), dim3(256), 0, stream,
                           adj1, adj2, Vt2, sQ, dE1, dE2, idxt, numPartB, zPart);
    } else {
        hipLaunchKernelGGL((k_mattn<4>), dim3(32 * 16), dim3(256), 0, stream,
                           adj1, adj2, Vt2, sQ, dE1, dE2, idxt, numPartB, zPart);
        hipLaunchKernelGGL((k_mattn<4>), dim3(32 * 16), dim3(256), 0, stream,
                           adj1, adj2, Vt2, sQ, dE1, dE2, idxt, numPartB, zPart);
    }
    hipLaunchKernelGGL(k_loss, dim3(NTRAIN / 4), dim3(256), 0, stream,
                       numPartB, zPart, labels, idxt, losses, scLog2);
    hipLaunchKernelGGL(k_reduce, dim3(1), dim3(256), 0, stream,
                       losses, (float*)d_out);
}

// Round 19
// 67.910 us; speedup vs baseline: 1.2350x; 1.2350x over previous
//
#include <hip/hip_runtime.h>
#include <hip/hip_bf16.h>

// GAT fused forward loss.
// R19: R18 measured T_mattn = 19.3us (NOT ~40 -- budget was wrong; the other
// ~45us is k_wh + k_loss + k_reduce + 4 launch gaps). This round: (1) drop
// k_reduce -- k_wh zeroes d_out, k_loss block-reduces + 1 atomicAdd/block;
// (2) k_wh 2-deep feat prefetch. k_mattn unchanged (R17, single launch).
// Structure: sampled rows (only h_all[idx_train] live), factored exp,
// MFMA j-amortization over 16 samples, Z via MFMA vs ones, grouped adj
// preload, sc-major block mapping, bf16 partials.

#define NN 8192
#define FTDIM 512
#define CDIM 64
#define NTRAIN 1024
#define LOG2E 1.44269504088896f

typedef __attribute__((ext_vector_type(8))) short short8;
typedef __attribute__((ext_vector_type(4))) float f32x4;
typedef __attribute__((ext_vector_type(4))) int i32x4;

static __device__ __forceinline__ unsigned short f2bf(float x) {
    return __bfloat16_as_ushort(__float2bfloat16(x));
}
static __device__ __forceinline__ float bf2f(unsigned short u) {
    return __uint_as_float((unsigned)u << 16);
}

// ---------------------------------------------------------------------------
// Kernel A: Wh = feat @ W, W LDS-staged, feat 2-deep prefetched. Block = 4
// waves; wave = 4 rows; 512 blocks. Two K-halves: stage W[half][256][64]
// (64KB), barrier, FMA with next k-step's feat loads already in flight.
// Epilogue: Vt2[jblk][c][e] = bf16(Wh[jblk*8+e][c]) + factored-exp tables
//   sQ[i]=(2^s', 2^(0.2s'), 2^(-s'));  dE1=2^d', dE2=2^(0.2d').
// Block 0 thread 0 zeroes d_out (k_loss atomicAdds into it).
// ---------------------------------------------------------------------------
__global__ __launch_bounds__(256) void k_wh(
    const float* __restrict__ feat, const float* __restrict__ W,
    const float* __restrict__ av, unsigned short* __restrict__ Vt2,
    float4* __restrict__ sQ, float* __restrict__ dE1, float* __restrict__ dE2,
    float* __restrict__ out)
{
    __shared__ float wlds[256 * CDIM];   // 64 KB

    const int tid  = threadIdx.x;
    const int lane = tid & 63;
    const int wv   = tid >> 6;
    const int gw   = blockIdx.x * 4 + wv;     // 0..2047
    const int row0 = gw * 4;
    const int c    = lane;

    if (blockIdx.x == 0 && tid == 0) out[0] = 0.f;   // k_loss accumulates

    float acc[4] = {0.f, 0.f, 0.f, 0.f};

#pragma unroll
    for (int half = 0; half < 2; ++half) {
        if (half) __syncthreads();
#pragma unroll
        for (int q = 0; q < 16; ++q) {
            const int idx = q * 256 + tid;
            *(f32x4*)&wlds[idx * 4] =
                *(const f32x4*)(W + half * (256 * CDIM) + idx * 4);
        }
        __syncthreads();

        const float* __restrict__ fb = feat + half * 256;
        f32x4 f[4], nf[4];
#pragma unroll
        for (int r = 0; r < 4; ++r)
            f[r] = *(const f32x4*)(fb + (size_t)(row0 + r) * FTDIM);

        for (int k = 0; k < 256; k += 4) {
            if (k + 4 < 256) {
#pragma unroll
                for (int r = 0; r < 4; ++r)
                    nf[r] = *(const f32x4*)(fb + (size_t)(row0 + r) * FTDIM + k + 4);
            }
#pragma unroll
            for (int kk = 0; kk < 4; ++kk) {
                const float wval = wlds[(k + kk) * CDIM + c];
#pragma unroll
                for (int r = 0; r < 4; ++r)
                    acc[r] = fmaf(f[r][kk], wval, acc[r]);
            }
#pragma unroll
            for (int r = 0; r < 4; ++r) f[r] = nf[r];
        }
    }

    ushort4 v4;
    v4.x = f2bf(acc[0]); v4.y = f2bf(acc[1]);
    v4.z = f2bf(acc[2]); v4.w = f2bf(acc[3]);
    *(ushort4*)(Vt2 + (size_t)(row0 >> 3) * 512 + c * 8 + (row0 & 7)) = v4;

    const float a1 = av[c], a2 = av[CDIM + c];
#pragma unroll
    for (int r = 0; r < 4; ++r) {
        float s_ = acc[r] * a1;
        float d_ = acc[r] * a2;
#pragma unroll
        for (int off = 32; off; off >>= 1) {
            s_ += __shfl_xor(s_, off);
            d_ += __shfl_xor(d_, off);
        }
        if (lane == 0) {
            const float sp = s_ * LOG2E, dp_ = d_ * LOG2E;
            sQ[row0 + r] = make_float4(__builtin_amdgcn_exp2f(sp),
                                       __builtin_amdgcn_exp2f(0.2f * sp),
                                       __builtin_amdgcn_exp2f(-sp), 0.f);
            dE1[row0 + r] = __builtin_amdgcn_exp2f(dp_);
            dE2[row0 + r] = __builtin_amdgcn_exp2f(0.2f * dp_);
        }
    }
}

// ---------------------------------------------------------------------------
// Kernel M (R17, unchanged): wave = (layer l, sample-block sb, chunk sc),
// sc-major block mapping (4 waves share the Vt2/dE window). Grouped adj
// preload -> mbits. Main loop: 2-deep pipeline; p = bit ? (e1>th ? E1*e1 :
// E2*e2) : 0 -> bf16 A-frag; 4 MFMAs + 1 vs ones = Z. numPart bf16.
// ---------------------------------------------------------------------------
struct TileS {
    f32x4 a0, a1, b0, b1;
    short8 v0, v1, v2, v3;
};

template<int SCL>
__global__ __launch_bounds__(256, 4) void k_mattn(
    const int* __restrict__ adj1, const int* __restrict__ adj2,
    const unsigned short* __restrict__ Vt2, const float4* __restrict__ sQ,
    const float* __restrict__ dE1, const float* __restrict__ dE2,
    const int* __restrict__ idxt,
    unsigned short* __restrict__ numPartB, float* __restrict__ zPart)
{
    constexpr int NT = (NN >> SCL) >> 5;
    const int lane = threadIdx.x & 63;
    const int w = (int)((blockIdx.x * blockDim.x + threadIdx.x) >> 6);
    const int l   = w >> (6 + SCL);
    const int rem = w & ((64 << SCL) - 1);
    const int sc  = rem >> 6;          // sc-major: block's 4 waves share sc
    const int sb  = rem & 63;

    const int r  = lane & 15;
    const int kg = lane >> 4;

    const int i = idxt[sb * 16 + r];
    const float4 sq = sQ[i];
    const float E1 = sq.x, E2 = sq.y, th = sq.z;

    const int j0 = sc * (NN >> SCL);
    const int* __restrict__ arow = (l ? adj2 : adj1) + (size_t)i * NN + j0 + kg * 8;
    const float* __restrict__ d1p = dE1 + j0 + kg * 8;
    const float* __restrict__ d2p = dE2 + j0 + kg * 8;
    const unsigned short* __restrict__ vbase =
        Vt2 + (((size_t)j0 >> 3) << 9) + ((size_t)kg << 9) + (r << 3);

    unsigned mbits[NT];
#pragma unroll
    for (int g = 0; g < NT; g += 4) {
        i32x4 gm0[4], gm1[4];
#pragma unroll
        for (int t = 0; t < 4; ++t) {
            gm0[t] = *(const i32x4*)(arow + (g + t) * 32);
            gm1[t] = *(const i32x4*)(arow + (g + t) * 32 + 4);
        }
#pragma unroll
        for (int t = 0; t < 4; ++t) {
            unsigned m = 0;
#pragma unroll
            for (int e = 0; e < 4; ++e) {
                m |= (gm0[t][e] != 0 ? 1u : 0u) << e;
                m |= (gm1[t][e] != 0 ? 1u : 0u) << (4 + e);
            }
            mbits[g + t] = m;
        }
    }

    short8 bOnes;
#pragma unroll
    for (int e = 0; e < 8; ++e) bOnes[e] = (short)0x3F80;   // bf16 1.0

    f32x4 acc0 = {0.f, 0.f, 0.f, 0.f};
    f32x4 acc1 = acc0, acc2 = acc0, acc3 = acc0, accz = acc0;

    TileS tA, tB;

#define LOADT(T, JT) do { const int _jr = (JT) * 32;                           \
    T.a0 = *(const f32x4*)(d1p + _jr);                                         \
    T.a1 = *(const f32x4*)(d1p + _jr + 4);                                     \
    T.b0 = *(const f32x4*)(d2p + _jr);                                         \
    T.b1 = *(const f32x4*)(d2p + _jr + 4);                                     \
    const unsigned short* _vp = vbase + ((size_t)(JT) << 11);                  \
    T.v0 = *(const short8*)(_vp);                                              \
    T.v1 = *(const short8*)(_vp + 128);                                        \
    T.v2 = *(const short8*)(_vp + 256);                                        \
    T.v3 = *(const short8*)(_vp + 384);                                        \
} while (0)

#define COMPT(T, JT) do {                                                      \
    const unsigned _mb = mbits[JT];                                            \
    short8 af;                                                                 \
    _Pragma("unroll")                                                          \
    for (int e = 0; e < 8; ++e) {                                              \
        const float e1 = (e < 4) ? T.a0[e & 3] : T.a1[e & 3];                  \
        const float e2 = (e < 4) ? T.b0[e & 3] : T.b1[e & 3];                  \
        const bool pos = e1 > th;                                              \
        float p = (pos ? e1 : e2) * (pos ? E1 : E2);                           \
        p = ((_mb >> e) & 1u) ? p : 0.f;                                       \
        af[e] = (short)f2bf(p);                                                \
    }                                                                          \
    acc0 = __builtin_amdgcn_mfma_f32_16x16x32_bf16(af, T.v0, acc0, 0, 0, 0);   \
    acc1 = __builtin_amdgcn_mfma_f32_16x16x32_bf16(af, T.v1, acc1, 0, 0, 0);   \
    acc2 = __builtin_amdgcn_mfma_f32_16x16x32_bf16(af, T.v2, acc2, 0, 0, 0);   \
    acc3 = __builtin_amdgcn_mfma_f32_16x16x32_bf16(af, T.v3, acc3, 0, 0, 0);   \
    accz = __builtin_amdgcn_mfma_f32_16x16x32_bf16(af, bOnes, accz, 0, 0, 0);  \
} while (0)

    LOADT(tA, 0);
#pragma unroll
    for (int jt = 0; jt < NT - 2; jt += 2) {
        LOADT(tB, jt + 1);
        COMPT(tA, jt);
        LOADT(tA, jt + 2);
        COMPT(tB, jt + 1);
    }
    LOADT(tB, NT - 1);
    COMPT(tA, NT - 2);
    COMPT(tB, NT - 1);
#undef LOADT
#undef COMPT

    constexpr int SC = 1 << SCL;
#pragma unroll
    for (int q = 0; q < 4; ++q) {
        const int ks = sb * 16 + kg * 4 + q;
        const size_t slot = ((size_t)ks * 2 + l) * SC + sc;
        unsigned short* op = numPartB + slot * CDIM + r;
        op[0]  = f2bf(acc0[q]);
        op[16] = f2bf(acc1[q]);
        op[32] = f2bf(acc2[q]);
        op[48] = f2bf(acc3[q]);
        if (r == 0) zPart[slot] = accz[q];
    }
}

// ---------------------------------------------------------------------------
// Kernel C: per-sample loss + final mean. One wave per sample k, lane = class.
// h = 0.5*(relu(n1/z1)+relu(n2/z2)); log-softmax over 64 lanes; NLL. Block
// reduces its 4 samples in LDS; ONE atomicAdd per block into out[0]
// (zeroed by k_wh; 256 atomics total; fp-order noise ~1e-6 << threshold).
// ---------------------------------------------------------------------------
__global__ __launch_bounds__(256) void k_loss(
    const unsigned short* __restrict__ numPartB, const float* __restrict__ zPart,
    const int* __restrict__ labels, const int* __restrict__ idxt,
    float* __restrict__ out, const int scLog2)
{
    __shared__ float lsum[4];
    const int tid = threadIdx.x;
    const int lane = tid & 63;
    const int wv = tid >> 6;
    const int k = (int)((blockIdx.x * blockDim.x + tid) >> 6);
    const int SC = 1 << scLog2;

    float logit = 0.f;
#pragma unroll
    for (int l = 0; l < 2; ++l) {
        const size_t base = ((size_t)k * 2 + l) * SC;
        float ns = 0.f;
#pragma unroll 16
        for (int s = 0; s < SC; ++s)
            ns += bf2f(numPartB[(base + s) * CDIM + lane]);
        float zs = (lane < SC) ? zPart[base + lane] : 0.f;
#pragma unroll
        for (int off = 32; off; off >>= 1) zs += __shfl_xor(zs, off);
        logit += fmaxf(ns / zs, 0.f);   // relu(elu(x)) == relu(x)
    }
    logit *= 0.5f;

    float m = logit;
#pragma unroll
    for (int off = 32; off; off >>= 1) m = fmaxf(m, __shfl_xor(m, off));
    float ex = __expf(logit - m);
    float sum = ex;
#pragma unroll
    for (int off = 32; off; off >>= 1) sum += __shfl_xor(sum, off);
    const float logp = logit - m - __logf(sum);

    const int y = labels[idxt[k]];
    const float t = __shfl(logp, y);
    if (lane == 0) lsum[wv] = -t;
    __syncthreads();
    if (tid == 0)
        atomicAdd(out, (lsum[0] + lsum[1] + lsum[2] + lsum[3]) * (1.f / 1024.f));
}

// ---------------------------------------------------------------------------
extern "C" void kernel_launch(void* const* d_in, const int* in_sizes, int n_in,
                              void* d_out, int out_size, void* d_ws, size_t ws_size,
                              hipStream_t stream)
{
    const float* feat   = (const float*)d_in[0];
    const float* W      = (const float*)d_in[1];
    const float* av     = (const float*)d_in[2];
    const int*   adj1   = (const int*)d_in[3];
    const int*   adj2   = (const int*)d_in[4];
    const int*   labels = (const int*)d_in[5];
    const int*   idxt   = (const int*)d_in[6];

    const size_t HEAD = (1u << 20) + (192u << 10);  // Vt2 1MB + sQ 128KB + dE1/2 64KB

    auto needed = [&](int scl) -> size_t {
        const size_t SC = (size_t)1 << scl;
        return HEAD + 2 * SC * NTRAIN * CDIM * sizeof(unsigned short)
                    + 2 * SC * NTRAIN * sizeof(float);
    };
    const int scLog2 = (ws_size >= needed(5)) ? 5 : 4;
    const int SC = 1 << scLog2;

    char* ws = (char*)d_ws;
    unsigned short* Vt2 = (unsigned short*)ws;                  // 1 MB
    float4* sQ  = (float4*)(ws + (1u << 20));                   // 128 KB
    float*  dE1 = (float*)(ws + (1u << 20) + (128u << 10));     // 32 KB
    float*  dE2 = (float*)(ws + (1u << 20) + (160u << 10));     // 32 KB
    unsigned short* numPartB = (unsigned short*)(ws + HEAD);
    float*  zPart  = (float*)((char*)numPartB
                              + 2ull * SC * NTRAIN * CDIM * sizeof(unsigned short));

    hipLaunchKernelGGL(k_wh, dim3(512), dim3(256), 0, stream,
                       feat, W, av, Vt2, sQ, dE1, dE2, (float*)d_out);
    if (scLog2 == 5)
        hipLaunchKernelGGL((k_mattn<5>), dim3(32 * 32), dim3(256), 0, stream,
                           adj1, adj2, Vt2, sQ, dE1, dE2, idxt, numPartB, zPart);
    else
        hipLaunchKernelGGL((k_mattn<4>), dim3(32 * 16), dim3(256), 0, stream,
                           adj1, adj2, Vt2, sQ, dE1, dE2, idxt, numPartB, zPart);
    hipLaunchKernelGGL(k_loss, dim3(NTRAIN / 4), dim3(256), 0, stream,
                       numPartB, zPart, labels, idxt, (float*)d_out, scLog2);
}

// Round 20
// 43.459 us; speedup vs baseline: 1.9298x; 1.5626x over previous
//
#include <hip/hip_runtime.h>
#include <hip/hip_bf16.h>

// GAT fused forward loss.
// R20: k_mattn measured at 19.3us = its 67MB @ 3.4TB/s read-wall floor (done).
// k_wh (~12-15us est.) rebuilt as MFMA GEMM: wave = 16 rows, A = contiguous
// feat bf16, B = short8 from L2-hot Wt2 (built by k_prep; Vt2-style layout,
// frag layouts verbatim from 18-round-verified k_mattn), 4-deep feat
// prefetch, no LDS/barriers. k_loss keeps fused mean (atomicAdd, bit-exact
// in R19). k_mattn unchanged (R17).
// Structure: sampled rows (only h_all[idx_train] live), factored exp,
// MFMA j-amortization, Z via MFMA vs ones, sc-major mapping, bf16 partials.

#define NN 8192
#define FTDIM 512
#define CDIM 64
#define NTRAIN 1024
#define LOG2E 1.44269504088896f

typedef __attribute__((ext_vector_type(8))) short short8;
typedef __attribute__((ext_vector_type(4))) float f32x4;
typedef __attribute__((ext_vector_type(4))) int i32x4;

static __device__ __forceinline__ unsigned short f2bf(float x) {
    return __bfloat16_as_ushort(__float2bfloat16(x));
}
static __device__ __forceinline__ float bf2f(unsigned short u) {
    return __uint_as_float((unsigned)u << 16);
}

// ---------------------------------------------------------------------------
// Kernel P: build Wt2[kblk][c][e] = bf16(W[kblk*8+e][c]) (64KB, L2-hot B
// operand for k_wh) and zero d_out. 16 blocks x 256 threads.
// ---------------------------------------------------------------------------
__global__ __launch_bounds__(256) void k_prep(
    const float* __restrict__ W, unsigned short* __restrict__ Wt2,
    float* __restrict__ out)
{
    if (blockIdx.x == 0 && threadIdx.x == 0) out[0] = 0.f;
    const int idx0 = blockIdx.x * 256 + threadIdx.x;
    for (int idx = idx0; idx < 64 * 64; idx += 16 * 256) {
        const int kblk = idx >> 6, c = idx & 63;
        short8 v;
#pragma unroll
        for (int e = 0; e < 8; ++e)
            v[e] = (short)f2bf(W[(kblk * 8 + e) * CDIM + c]);
        *(short8*)(Wt2 + (size_t)idx * 8) = v;
    }
}

// ---------------------------------------------------------------------------
// Kernel A: Wh = feat @ W via MFMA 16x16x32. One wave (64-thr block) per 16
// rows; 512 blocks (2 waves/CU). Lane (r=lane&15, kg=lane>>4). Per k-iter
// (K=512 -> 16 iters): A-frag = bf16(feat[row0+r][k0+kg*8..+8]) (32B
// contiguous, 4-deep prefetched); B-frag[nt] = short8 Wt2[(k0>>3)+kg][nt*16+r]
// (L2-hot); 4 MFMAs. D: lane holds Wh[row0+kg*4+q][nt*16+r].
// Epilogue: Vt2[jblk][c][e]=bf16(Wh[jblk*8+e][c]) via packed ushort4;
// s,d row-sums via 4x shfl_xor within 16-lane groups; factored-exp tables
//   sQ[i]=(2^s', 2^(0.2s'), 2^(-s'));  dE1=2^d', dE2=2^(0.2d').
// ---------------------------------------------------------------------------
__global__ __launch_bounds__(64) void k_wh(
    const float* __restrict__ feat, const unsigned short* __restrict__ Wt2,
    const float* __restrict__ av, unsigned short* __restrict__ Vt2,
    float4* __restrict__ sQ, float* __restrict__ dE1, float* __restrict__ dE2)
{
    const int lane = threadIdx.x;
    const int r  = lane & 15;
    const int kg = lane >> 4;
    const int row0 = blockIdx.x * 16;

    const float* __restrict__ fp = feat + (size_t)(row0 + r) * FTDIM + kg * 8;

    f32x4 fa[4], fb[4];   // 4-deep prefetch ring (2 f32x4 per A-frag)
#pragma unroll
    for (int d = 0; d < 4; ++d) {
        fa[d] = *(const f32x4*)(fp + d * 32);
        fb[d] = *(const f32x4*)(fp + d * 32 + 4);
    }

    f32x4 acc0 = {0.f, 0.f, 0.f, 0.f};
    f32x4 acc1 = acc0, acc2 = acc0, acc3 = acc0;

    for (int it = 0; it < 16; ++it) {
        const int slot = it & 3;
        const f32x4 a0 = fa[slot], a1 = fb[slot];
        if (it + 4 < 16) {
            fa[slot] = *(const f32x4*)(fp + (it + 4) * 32);
            fb[slot] = *(const f32x4*)(fp + (it + 4) * 32 + 4);
        }

        short8 af;
#pragma unroll
        for (int e = 0; e < 4; ++e) {
            af[e]     = (short)f2bf(a0[e]);
            af[4 + e] = (short)f2bf(a1[e]);
        }

        const unsigned short* bp = Wt2 + ((size_t)(it * 4 + kg)) * 512 + (r << 3);
        const short8 b0 = *(const short8*)(bp);
        const short8 b1 = *(const short8*)(bp + 128);
        const short8 b2 = *(const short8*)(bp + 256);
        const short8 b3 = *(const short8*)(bp + 384);

        acc0 = __builtin_amdgcn_mfma_f32_16x16x32_bf16(af, b0, acc0, 0, 0, 0);
        acc1 = __builtin_amdgcn_mfma_f32_16x16x32_bf16(af, b1, acc1, 0, 0, 0);
        acc2 = __builtin_amdgcn_mfma_f32_16x16x32_bf16(af, b2, acc2, 0, 0, 0);
        acc3 = __builtin_amdgcn_mfma_f32_16x16x32_bf16(af, b3, acc3, 0, 0, 0);
    }

    // ---- Vt2 store: rows row0+kg*4+q, cols nt*16+r ----
    const size_t jblk = (size_t)(row0 >> 3) + (kg >> 1);
    const int e0 = (kg & 1) * 4;
#pragma unroll
    for (int nt = 0; nt < 4; ++nt) {
        const f32x4 a = (nt == 0) ? acc0 : (nt == 1) ? acc1 : (nt == 2) ? acc2 : acc3;
        ushort4 v4;
        v4.x = f2bf(a[0]); v4.y = f2bf(a[1]); v4.z = f2bf(a[2]); v4.w = f2bf(a[3]);
        *(ushort4*)(Vt2 + jblk * 512 + (size_t)(nt * 16 + r) * 8 + e0) = v4;
    }

    // ---- s,d: per-lane partial over its 4 cols, reduce over 16-lane group ----
    float a1v[4], a2v[4];
#pragma unroll
    for (int nt = 0; nt < 4; ++nt) {
        a1v[nt] = av[nt * 16 + r];
        a2v[nt] = av[CDIM + nt * 16 + r];
    }
#pragma unroll
    for (int q = 0; q < 4; ++q) {
        float s_ = acc0[q] * a1v[0] + acc1[q] * a1v[1]
                 + acc2[q] * a1v[2] + acc3[q] * a1v[3];
        float d_ = acc0[q] * a2v[0] + acc1[q] * a2v[1]
                 + acc2[q] * a2v[2] + acc3[q] * a2v[3];
#pragma unroll
        for (int off = 8; off; off >>= 1) {
            s_ += __shfl_xor(s_, off);
            d_ += __shfl_xor(d_, off);
        }
        if (r == 0) {
            const int i = row0 + kg * 4 + q;
            const float sp = s_ * LOG2E, dp_ = d_ * LOG2E;
            sQ[i] = make_float4(__builtin_amdgcn_exp2f(sp),
                                __builtin_amdgcn_exp2f(0.2f * sp),
                                __builtin_amdgcn_exp2f(-sp), 0.f);
            dE1[i] = __builtin_amdgcn_exp2f(dp_);
            dE2[i] = __builtin_amdgcn_exp2f(0.2f * dp_);
        }
    }
}

// ---------------------------------------------------------------------------
// Kernel M (R17, unchanged): wave = (layer l, sample-block sb, chunk sc),
// sc-major block mapping. Grouped adj preload -> mbits. 2-deep pipeline;
// p = bit ? (e1>th ? E1*e1 : E2*e2) : 0 -> bf16 A-frag; 4 MFMAs + 1 vs ones.
// At the 67MB @ 3.4TB/s read wall (measured 19.3us R18) -- do not touch.
// ---------------------------------------------------------------------------
struct TileS {
    f32x4 a0, a1, b0, b1;
    short8 v0, v1, v2, v3;
};

template<int SCL>
__global__ __launch_bounds__(256, 4) void k_mattn(
    const int* __restrict__ adj1, const int* __restrict__ adj2,
    const unsigned short* __restrict__ Vt2, const float4* __restrict__ sQ,
    const float* __restrict__ dE1, const float* __restrict__ dE2,
    const int* __restrict__ idxt,
    unsigned short* __restrict__ numPartB, float* __restrict__ zPart)
{
    constexpr int NT = (NN >> SCL) >> 5;
    const int lane = threadIdx.x & 63;
    const int w = (int)((blockIdx.x * blockDim.x + threadIdx.x) >> 6);
    const int l   = w >> (6 + SCL);
    const int rem = w & ((64 << SCL) - 1);
    const int sc  = rem >> 6;
    const int sb  = rem & 63;

    const int r  = lane & 15;
    const int kg = lane >> 4;

    const int i = idxt[sb * 16 + r];
    const float4 sq = sQ[i];
    const float E1 = sq.x, E2 = sq.y, th = sq.z;

    const int j0 = sc * (NN >> SCL);
    const int* __restrict__ arow = (l ? adj2 : adj1) + (size_t)i * NN + j0 + kg * 8;
    const float* __restrict__ d1p = dE1 + j0 + kg * 8;
    const float* __restrict__ d2p = dE2 + j0 + kg * 8;
    const unsigned short* __restrict__ vbase =
        Vt2 + (((size_t)j0 >> 3) << 9) + ((size_t)kg << 9) + (r << 3);

    unsigned mbits[NT];
#pragma unroll
    for (int g = 0; g < NT; g += 4) {
        i32x4 gm0[4], gm1[4];
#pragma unroll
        for (int t = 0; t < 4; ++t) {
            gm0[t] = *(const i32x4*)(arow + (g + t) * 32);
            gm1[t] = *(const i32x4*)(arow + (g + t) * 32 + 4);
        }
#pragma unroll
        for (int t = 0; t < 4; ++t) {
            unsigned m = 0;
#pragma unroll
            for (int e = 0; e < 4; ++e) {
                m |= (gm0[t][e] != 0 ? 1u : 0u) << e;
                m |= (gm1[t][e] != 0 ? 1u : 0u) << (4 + e);
            }
            mbits[g + t] = m;
        }
    }

    short8 bOnes;
#pragma unroll
    for (int e = 0; e < 8; ++e) bOnes[e] = (short)0x3F80;

    f32x4 acc0 = {0.f, 0.f, 0.f, 0.f};
    f32x4 acc1 = acc0, acc2 = acc0, acc3 = acc0, accz = acc0;

    TileS tA, tB;

#define LOADT(T, JT) do { const int _jr = (JT) * 32;                           \
    T.a0 = *(const f32x4*)(d1p + _jr);                                         \
    T.a1 = *(const f32x4*)(d1p + _jr + 4);                                     \
    T.b0 = *(const f32x4*)(d2p + _jr);                                         \
    T.b1 = *(const f32x4*)(d2p + _jr + 4);                                     \
    const unsigned short* _vp = vbase + ((size_t)(JT) << 11);                  \
    T.v0 = *(const short8*)(_vp);                                              \
    T.v1 = *(const short8*)(_vp + 128);                                        \
    T.v2 = *(const short8*)(_vp + 256);                                        \
    T.v3 = *(const short8*)(_vp + 384);                                        \
} while (0)

#define COMPT(T, JT) do {                                                      \
    const unsigned _mb = mbits[JT];                                            \
    short8 af;                                                                 \
    _Pragma("unroll")                                                          \
    for (int e = 0; e < 8; ++e) {                                              \
        const float e1 = (e < 4) ? T.a0[e & 3] : T.a1[e & 3];                  \
        const float e2 = (e < 4) ? T.b0[e & 3] : T.b1[e & 3];                  \
        const bool pos = e1 > th;                                              \
        float p = (pos ? e1 : e2) * (pos ? E1 : E2);                           \
        p = ((_mb >> e) & 1u) ? p : 0.f;                                       \
        af[e] = (short)f2bf(p);                                                \
    }                                                                          \
    acc0 = __builtin_amdgcn_mfma_f32_16x16x32_bf16(af, T.v0, acc0, 0, 0, 0);   \
    acc1 = __builtin_amdgcn_mfma_f32_16x16x32_bf16(af, T.v1, acc1, 0, 0, 0);   \
    acc2 = __builtin_amdgcn_mfma_f32_16x16x32_bf16(af, T.v2, acc2, 0, 0, 0);   \
    acc3 = __builtin_amdgcn_mfma_f32_16x16x32_bf16(af, T.v3, acc3, 0, 0, 0);   \
    accz = __builtin_amdgcn_mfma_f32_16x16x32_bf16(af, bOnes, accz, 0, 0, 0);  \
} while (0)

    LOADT(tA, 0);
#pragma unroll
    for (int jt = 0; jt < NT - 2; jt += 2) {
        LOADT(tB, jt + 1);
        COMPT(tA, jt);
        LOADT(tA, jt + 2);
        COMPT(tB, jt + 1);
    }
    LOADT(tB, NT - 1);
    COMPT(tA, NT - 2);
    COMPT(tB, NT - 1);
#undef LOADT
#undef COMPT

    constexpr int SC = 1 << SCL;
#pragma unroll
    for (int q = 0; q < 4; ++q) {
        const int ks = sb * 16 + kg * 4 + q;
        const size_t slot = ((size_t)ks * 2 + l) * SC + sc;
        unsigned short* op = numPartB + slot * CDIM + r;
        op[0]  = f2bf(acc0[q]);
        op[16] = f2bf(acc1[q]);
        op[32] = f2bf(acc2[q]);
        op[48] = f2bf(acc3[q]);
        if (r == 0) zPart[slot] = accz[q];
    }
}

// ---------------------------------------------------------------------------
// Kernel C: per-sample loss + fused mean. One wave per sample k, lane=class.
// Block LDS-reduces its 4 samples; ONE atomicAdd per block into out[0]
// (zeroed by k_prep). Bit-exact pass in R19.
// ---------------------------------------------------------------------------
__global__ __launch_bounds__(256) void k_loss(
    const unsigned short* __restrict__ numPartB, const float* __restrict__ zPart,
    const int* __restrict__ labels, const int* __restrict__ idxt,
    float* __restrict__ out, const int scLog2)
{
    __shared__ float lsum[4];
    const int tid = threadIdx.x;
    const int lane = tid & 63;
    const int wv = tid >> 6;
    const int k = (int)((blockIdx.x * blockDim.x + tid) >> 6);
    const int SC = 1 << scLog2;

    float logit = 0.f;
#pragma unroll
    for (int l = 0; l < 2; ++l) {
        const size_t base = ((size_t)k * 2 + l) * SC;
        float ns = 0.f;
#pragma unroll 16
        for (int s = 0; s < SC; ++s)
            ns += bf2f(numPartB[(base + s) * CDIM + lane]);
        float zs = (lane < SC) ? zPart[base + lane] : 0.f;
#pragma unroll
        for (int off = 32; off; off >>= 1) zs += __shfl_xor(zs, off);
        logit += fmaxf(ns / zs, 0.f);   // relu(elu(x)) == relu(x)
    }
    logit *= 0.5f;

    float m = logit;
#pragma unroll
    for (int off = 32; off; off >>= 1) m = fmaxf(m, __shfl_xor(m, off));
    float ex = __expf(logit - m);
    float sum = ex;
#pragma unroll
    for (int off = 32; off; off >>= 1) sum += __shfl_xor(sum, off);
    const float logp = logit - m - __logf(sum);

    const int y = labels[idxt[k]];
    const float t = __shfl(logp, y);
    if (lane == 0) lsum[wv] = -t;
    __syncthreads();
    if (tid == 0)
        atomicAdd(out, (lsum[0] + lsum[1] + lsum[2] + lsum[3]) * (1.f / 1024.f));
}

// ---------------------------------------------------------------------------
extern "C" void kernel_launch(void* const* d_in, const int* in_sizes, int n_in,
                              void* d_out, int out_size, void* d_ws, size_t ws_size,
                              hipStream_t stream)
{
    const float* feat   = (const float*)d_in[0];
    const float* W      = (const float*)d_in[1];
    const float* av     = (const float*)d_in[2];
    const int*   adj1   = (const int*)d_in[3];
    const int*   adj2   = (const int*)d_in[4];
    const int*   labels = (const int*)d_in[5];
    const int*   idxt   = (const int*)d_in[6];

    // head: Vt2 1MB | Wt2 64KB | sQ 128KB | dE1 32KB | dE2 32KB
    const size_t HEAD = (1u << 20) + (256u << 10);

    auto needed = [&](int scl) -> size_t {
        const size_t SC = (size_t)1 << scl;
        return HEAD + 2 * SC * NTRAIN * CDIM * sizeof(unsigned short)
                    + 2 * SC * NTRAIN * sizeof(float);
    };
    const int scLog2 = (ws_size >= needed(5)) ? 5 : 4;
    const int SC = 1 << scLog2;

    char* ws = (char*)d_ws;
    unsigned short* Vt2 = (unsigned short*)ws;                       // 1 MB
    unsigned short* Wt2 = (unsigned short*)(ws + (1u << 20));        // 64 KB
    float4* sQ  = (float4*)(ws + (1u << 20) + (64u << 10));          // 128 KB
    float*  dE1 = (float*)(ws + (1u << 20) + (192u << 10));          // 32 KB
    float*  dE2 = (float*)(ws + (1u << 20) + (224u << 10));          // 32 KB
    unsigned short* numPartB = (unsigned short*)(ws + HEAD);
    float*  zPart  = (float*)((char*)numPartB
                              + 2ull * SC * NTRAIN * CDIM * sizeof(unsigned short));

    hipLaunchKernelGGL(k_prep, dim3(16), dim3(256), 0, stream,
                       W, Wt2, (float*)d_out);
    hipLaunchKernelGGL(k_wh, dim3(512), dim3(64), 0, stream,
                       feat, Wt2, av, Vt2, sQ, dE1, dE2);
    if (scLog2 == 5)
        hipLaunchKernelGGL((k_mattn<5>), dim3(32 * 32), dim3(256), 0, stream,
                           adj1, adj2, Vt2, sQ, dE1, dE2, idxt, numPartB, zPart);
    else
        hipLaunchKernelGGL((k_mattn<4>), dim3(32 * 16), dim3(256), 0, stream,
                           adj1, adj2, Vt2, sQ, dE1, dE2, idxt, numPartB, zPart);
    hipLaunchKernelGGL(k_loss, dim3(NTRAIN / 4), dim3(256), 0, stream,
                       numPartB, zPart, labels, idxt, (float*)d_out, scLog2);
}

// Round 21
// 42.143 us; speedup vs baseline: 1.9901x; 1.0312x over previous
//
#include <hip/hip_runtime.h>
#include <hip/hip_bf16.h>

// GAT fused forward loss.
// R21: split the adj read out of k_mattn. k_madj packs the ~960 sampled rows
// (L3-resident on replays) with R5's proven sequential lane-contiguous
// pattern into a 2MB bitmask (+ builds Wt2, zeros d_out); k_mattn2's gather
// prologue becomes NT/2 u64 mask loads + byte extracts. k_wh = R20 MFMA GEMM
// (64.6->43.5 win). k_loss unchanged.
// Mask layout: u16 per 16 consecutive j, bit = j&15 => byte addr j>>3,
// bit j&7. Consumer tile t, lane kg: byte ((t&1)*4+kg) of u64 #(t>>1).

#define NN 8192
#define FTDIM 512
#define CDIM 64
#define NTRAIN 1024
#define LOG2E 1.44269504088896f

typedef __attribute__((ext_vector_type(8))) short short8;
typedef __attribute__((ext_vector_type(4))) float f32x4;
typedef __attribute__((ext_vector_type(4))) int i32x4;

static __device__ __forceinline__ unsigned short f2bf(float x) {
    return __bfloat16_as_ushort(__float2bfloat16(x));
}
static __device__ __forceinline__ float bf2f(unsigned short u) {
    return __uint_as_float((unsigned)u << 16);
}

// ---------------------------------------------------------------------------
// Kernel J: pack sampled adj rows -> maskB (2MB) + build Wt2 + zero d_out.
// 1024 blocks x 256. Wave w2 = half-row of (l,ks): row i = idxt[ks].
// Per iter (4): lane reads 16 consecutive ints (4x i32x4, instruction-
// contiguous 1KB/64-lane) -> u16 (bit = j&15) -> coalesced store.
// Blocks 0..15 additionally build Wt2[kblk][c][e] = bf16(W[kblk*8+e][c]).
// ---------------------------------------------------------------------------
__global__ __launch_bounds__(256) void k_madj(
    const int* __restrict__ adj1, const int* __restrict__ adj2,
    const int* __restrict__ idxt, const float* __restrict__ W,
    unsigned short* __restrict__ Wt2, unsigned short* __restrict__ maskB,
    float* __restrict__ out)
{
    const int tid = threadIdx.x;

    if (blockIdx.x < 16) {
        const int idx = blockIdx.x * 256 + tid;    // 0..4095
        const int kblk = idx >> 6, c = idx & 63;
        short8 v;
#pragma unroll
        for (int e = 0; e < 8; ++e)
            v[e] = (short)f2bf(W[(kblk * 8 + e) * CDIM + c]);
        *(short8*)(Wt2 + (size_t)idx * 8) = v;
        if (blockIdx.x == 0 && tid == 0) out[0] = 0.f;
    }

    const int lane = tid & 63;
    const int w2   = blockIdx.x * 4 + (tid >> 6);  // 0..4095
    const int half = w2 & 1;
    const int row  = w2 >> 1;                      // l*1024 + ks
    const int l    = row >> 10;
    const int ks   = row & 1023;
    const int i    = idxt[ks];

    const int* __restrict__ arow = (l ? adj2 : adj1) + (size_t)i * NN + half * 4096;
    unsigned short* __restrict__ mrow = maskB + (size_t)row * 512 + half * 256;

#pragma unroll
    for (int u = 0; u < 4; ++u) {
        const int lb = u * 1024 + lane * 16;
        const i32x4 a0 = *(const i32x4*)(arow + lb);
        const i32x4 a1 = *(const i32x4*)(arow + lb + 4);
        const i32x4 a2 = *(const i32x4*)(arow + lb + 8);
        const i32x4 a3 = *(const i32x4*)(arow + lb + 12);
        unsigned m = 0;
#pragma unroll
        for (int e = 0; e < 4; ++e) {
            m |= (a0[e] != 0 ? 1u : 0u) << e;
            m |= (a1[e] != 0 ? 1u : 0u) << (4 + e);
            m |= (a2[e] != 0 ? 1u : 0u) << (8 + e);
            m |= (a3[e] != 0 ? 1u : 0u) << (12 + e);
        }
        mrow[u * 64 + lane] = (unsigned short)m;
    }
}

// ---------------------------------------------------------------------------
// Kernel A (R20): Wh = feat @ W via MFMA 16x16x32. One wave per 16 rows;
// 512 blocks. A-frag = contiguous feat bf16 (4-deep prefetch); B-frags =
// short8 from L2-hot Wt2. Epilogue: Vt2 + factored-exp tables
//   sQ[i]=(2^s', 2^(0.2s'), 2^(-s'));  dE1=2^d', dE2=2^(0.2d').
// ---------------------------------------------------------------------------
__global__ __launch_bounds__(64) void k_wh(
    const float* __restrict__ feat, const unsigned short* __restrict__ Wt2,
    const float* __restrict__ av, unsigned short* __restrict__ Vt2,
    float4* __restrict__ sQ, float* __restrict__ dE1, float* __restrict__ dE2)
{
    const int lane = threadIdx.x;
    const int r  = lane & 15;
    const int kg = lane >> 4;
    const int row0 = blockIdx.x * 16;

    const float* __restrict__ fp = feat + (size_t)(row0 + r) * FTDIM + kg * 8;

    f32x4 fa[4], fb[4];
#pragma unroll
    for (int d = 0; d < 4; ++d) {
        fa[d] = *(const f32x4*)(fp + d * 32);
        fb[d] = *(const f32x4*)(fp + d * 32 + 4);
    }

    f32x4 acc0 = {0.f, 0.f, 0.f, 0.f};
    f32x4 acc1 = acc0, acc2 = acc0, acc3 = acc0;

    for (int it = 0; it < 16; ++it) {
        const int slot = it & 3;
        const f32x4 a0 = fa[slot], a1 = fb[slot];
        if (it + 4 < 16) {
            fa[slot] = *(const f32x4*)(fp + (it + 4) * 32);
            fb[slot] = *(const f32x4*)(fp + (it + 4) * 32 + 4);
        }

        short8 af;
#pragma unroll
        for (int e = 0; e < 4; ++e) {
            af[e]     = (short)f2bf(a0[e]);
            af[4 + e] = (short)f2bf(a1[e]);
        }

        const unsigned short* bp = Wt2 + ((size_t)(it * 4 + kg)) * 512 + (r << 3);
        const short8 b0 = *(const short8*)(bp);
        const short8 b1 = *(const short8*)(bp + 128);
        const short8 b2 = *(const short8*)(bp + 256);
        const short8 b3 = *(const short8*)(bp + 384);

        acc0 = __builtin_amdgcn_mfma_f32_16x16x32_bf16(af, b0, acc0, 0, 0, 0);
        acc1 = __builtin_amdgcn_mfma_f32_16x16x32_bf16(af, b1, acc1, 0, 0, 0);
        acc2 = __builtin_amdgcn_mfma_f32_16x16x32_bf16(af, b2, acc2, 0, 0, 0);
        acc3 = __builtin_amdgcn_mfma_f32_16x16x32_bf16(af, b3, acc3, 0, 0, 0);
    }

    const size_t jblk = (size_t)(row0 >> 3) + (kg >> 1);
    const int e0 = (kg & 1) * 4;
#pragma unroll
    for (int nt = 0; nt < 4; ++nt) {
        const f32x4 a = (nt == 0) ? acc0 : (nt == 1) ? acc1 : (nt == 2) ? acc2 : acc3;
        ushort4 v4;
        v4.x = f2bf(a[0]); v4.y = f2bf(a[1]); v4.z = f2bf(a[2]); v4.w = f2bf(a[3]);
        *(ushort4*)(Vt2 + jblk * 512 + (size_t)(nt * 16 + r) * 8 + e0) = v4;
    }

    float a1v[4], a2v[4];
#pragma unroll
    for (int nt = 0; nt < 4; ++nt) {
        a1v[nt] = av[nt * 16 + r];
        a2v[nt] = av[CDIM + nt * 16 + r];
    }
#pragma unroll
    for (int q = 0; q < 4; ++q) {
        float s_ = acc0[q] * a1v[0] + acc1[q] * a1v[1]
                 + acc2[q] * a1v[2] + acc3[q] * a1v[3];
        float d_ = acc0[q] * a2v[0] + acc1[q] * a2v[1]
                 + acc2[q] * a2v[2] + acc3[q] * a2v[3];
#pragma unroll
        for (int off = 8; off; off >>= 1) {
            s_ += __shfl_xor(s_, off);
            d_ += __shfl_xor(d_, off);
        }
        if (r == 0) {
            const int i = row0 + kg * 4 + q;
            const float sp = s_ * LOG2E, dp_ = d_ * LOG2E;
            sQ[i] = make_float4(__builtin_amdgcn_exp2f(sp),
                                __builtin_amdgcn_exp2f(0.2f * sp),
                                __builtin_amdgcn_exp2f(-sp), 0.f);
            dE1[i] = __builtin_amdgcn_exp2f(dp_);
            dE2[i] = __builtin_amdgcn_exp2f(0.2f * dp_);
        }
    }
}

// ---------------------------------------------------------------------------
// Kernel M2: R17 main loop, adj gather replaced by NT/2 u64 mask loads
// (L2-resident 2MB) + byte extracts. sc-major mapping, bf16 partials.
// ---------------------------------------------------------------------------
struct TileS {
    f32x4 a0, a1, b0, b1;
    short8 v0, v1, v2, v3;
};

template<int SCL>
__global__ __launch_bounds__(256, 4) void k_mattn(
    const unsigned short* __restrict__ maskB,
    const unsigned short* __restrict__ Vt2, const float4* __restrict__ sQ,
    const float* __restrict__ dE1, const float* __restrict__ dE2,
    const int* __restrict__ idxt,
    unsigned short* __restrict__ numPartB, float* __restrict__ zPart)
{
    constexpr int NT = (NN >> SCL) >> 5;
    const int lane = threadIdx.x & 63;
    const int w = (int)((blockIdx.x * blockDim.x + threadIdx.x) >> 6);
    const int l   = w >> (6 + SCL);
    const int rem = w & ((64 << SCL) - 1);
    const int sc  = rem >> 6;
    const int sb  = rem & 63;

    const int r  = lane & 15;
    const int kg = lane >> 4;

    const int ks = sb * 16 + r;
    const int i = idxt[ks];
    const float4 sq = sQ[i];
    const float E1 = sq.x, E2 = sq.y, th = sq.z;

    const int j0 = sc * (NN >> SCL);
    const float* __restrict__ d1p = dE1 + j0 + kg * 8;
    const float* __restrict__ d2p = dE2 + j0 + kg * 8;
    const unsigned short* __restrict__ vbase =
        Vt2 + (((size_t)j0 >> 3) << 9) + ((size_t)kg << 9) + (r << 3);

    // ---- mask preload: NT/2 u64s from maskB row (l*1024+ks), offset j0/8 ----
    const unsigned long long* __restrict__ mptr =
        (const unsigned long long*)((const char*)maskB
            + (size_t)((l << 10) + ks) * 1024 + (j0 >> 3));
    unsigned long long mw[NT / 2];
#pragma unroll
    for (int ww = 0; ww < NT / 2; ++ww) mw[ww] = mptr[ww];

    unsigned mbits[NT];
#pragma unroll
    for (int t = 0; t < NT; ++t)
        mbits[t] = (unsigned)(mw[t >> 1] >> (((t & 1) * 4 + kg) * 8)) & 0xffu;

    short8 bOnes;
#pragma unroll
    for (int e = 0; e < 8; ++e) bOnes[e] = (short)0x3F80;

    f32x4 acc0 = {0.f, 0.f, 0.f, 0.f};
    f32x4 acc1 = acc0, acc2 = acc0, acc3 = acc0, accz = acc0;

    TileS tA, tB;

#define LOADT(T, JT) do { const int _jr = (JT) * 32;                           \
    T.a0 = *(const f32x4*)(d1p + _jr);                                         \
    T.a1 = *(const f32x4*)(d1p + _jr + 4);                                     \
    T.b0 = *(const f32x4*)(d2p + _jr);                                         \
    T.b1 = *(const f32x4*)(d2p + _jr + 4);                                     \
    const unsigned short* _vp = vbase + ((size_t)(JT) << 11);                  \
    T.v0 = *(const short8*)(_vp);                                              \
    T.v1 = *(const short8*)(_vp + 128);                                        \
    T.v2 = *(const short8*)(_vp + 256);                                        \
    T.v3 = *(const short8*)(_vp + 384);                                        \
} while (0)

#define COMPT(T, JT) do {                                                      \
    const unsigned _mb = mbits[JT];                                            \
    short8 af;                                                                 \
    _Pragma("unroll")                                                          \
    for (int e = 0; e < 8; ++e) {                                              \
        const float e1 = (e < 4) ? T.a0[e & 3] : T.a1[e & 3];                  \
        const float e2 = (e < 4) ? T.b0[e & 3] : T.b1[e & 3];                  \
        const bool pos = e1 > th;                                              \
        float p = (pos ? e1 : e2) * (pos ? E1 : E2);                           \
        p = ((_mb >> e) & 1u) ? p : 0.f;                                       \
        af[e] = (short)f2bf(p);                                                \
    }                                                                          \
    acc0 = __builtin_amdgcn_mfma_f32_16x16x32_bf16(af, T.v0, acc0, 0, 0, 0);   \
    acc1 = __builtin_amdgcn_mfma_f32_16x16x32_bf16(af, T.v1, acc1, 0, 0, 0);   \
    acc2 = __builtin_amdgcn_mfma_f32_16x16x32_bf16(af, T.v2, acc2, 0, 0, 0);   \
    acc3 = __builtin_amdgcn_mfma_f32_16x16x32_bf16(af, T.v3, acc3, 0, 0, 0);   \
    accz = __builtin_amdgcn_mfma_f32_16x16x32_bf16(af, bOnes, accz, 0, 0, 0);  \
} while (0)

    LOADT(tA, 0);
#pragma unroll
    for (int jt = 0; jt < NT - 2; jt += 2) {
        LOADT(tB, jt + 1);
        COMPT(tA, jt);
        LOADT(tA, jt + 2);
        COMPT(tB, jt + 1);
    }
    LOADT(tB, NT - 1);
    COMPT(tA, NT - 2);
    COMPT(tB, NT - 1);
#undef LOADT
#undef COMPT

    constexpr int SC = 1 << SCL;
#pragma unroll
    for (int q = 0; q < 4; ++q) {
        const int kss = sb * 16 + kg * 4 + q;
        const size_t slot = ((size_t)kss * 2 + l) * SC + sc;
        unsigned short* op = numPartB + slot * CDIM + r;
        op[0]  = f2bf(acc0[q]);
        op[16] = f2bf(acc1[q]);
        op[32] = f2bf(acc2[q]);
        op[48] = f2bf(acc3[q]);
        if (r == 0) zPart[slot] = accz[q];
    }
}

// ---------------------------------------------------------------------------
// Kernel C: per-sample loss + fused mean (atomicAdd into out, zeroed by
// k_madj). Bit-exact pass since R19.
// ---------------------------------------------------------------------------
__global__ __launch_bounds__(256) void k_loss(
    const unsigned short* __restrict__ numPartB, const float* __restrict__ zPart,
    const int* __restrict__ labels, const int* __restrict__ idxt,
    float* __restrict__ out, const int scLog2)
{
    __shared__ float lsum[4];
    const int tid = threadIdx.x;
    const int lane = tid & 63;
    const int wv = tid >> 6;
    const int k = (int)((blockIdx.x * blockDim.x + tid) >> 6);
    const int SC = 1 << scLog2;

    float logit = 0.f;
#pragma unroll
    for (int l = 0; l < 2; ++l) {
        const size_t base = ((size_t)k * 2 + l) * SC;
        float ns = 0.f;
#pragma unroll 16
        for (int s = 0; s < SC; ++s)
            ns += bf2f(numPartB[(base + s) * CDIM + lane]);
        float zs = (lane < SC) ? zPart[base + lane] : 0.f;
#pragma unroll
        for (int off = 32; off; off >>= 1) zs += __shfl_xor(zs, off);
        logit += fmaxf(ns / zs, 0.f);   // relu(elu(x)) == relu(x)
    }
    logit *= 0.5f;

    float m = logit;
#pragma unroll
    for (int off = 32; off; off >>= 1) m = fmaxf(m, __shfl_xor(m, off));
    float ex = __expf(logit - m);
    float sum = ex;
#pragma unroll
    for (int off = 32; off; off >>= 1) sum += __shfl_xor(sum, off);
    const float logp = logit - m - __logf(sum);

    const int y = labels[idxt[k]];
    const float t = __shfl(logp, y);
    if (lane == 0) lsum[wv] = -t;
    __syncthreads();
    if (tid == 0)
        atomicAdd(out, (lsum[0] + lsum[1] + lsum[2] + lsum[3]) * (1.f / 1024.f));
}

// ---------------------------------------------------------------------------
extern "C" void kernel_launch(void* const* d_in, const int* in_sizes, int n_in,
                              void* d_out, int out_size, void* d_ws, size_t ws_size,
                              hipStream_t stream)
{
    const float* feat   = (const float*)d_in[0];
    const float* W      = (const float*)d_in[1];
    const float* av     = (const float*)d_in[2];
    const int*   adj1   = (const int*)d_in[3];
    const int*   adj2   = (const int*)d_in[4];
    const int*   labels = (const int*)d_in[5];
    const int*   idxt   = (const int*)d_in[6];

    // head: Vt2 1MB | Wt2 64KB | sQ 128KB | dE1 32KB | dE2 32KB | maskB 2MB
    const size_t MASKB = 2ull * NTRAIN * (NN / 8);         // 2 MB
    const size_t HEAD  = (1u << 20) + (256u << 10) + MASKB;

    auto needed = [&](int scl) -> size_t {
        const size_t SC = (size_t)1 << scl;
        return HEAD + 2 * SC * NTRAIN * CDIM * sizeof(unsigned short)
                    + 2 * SC * NTRAIN * sizeof(float);
    };
    const int scLog2 = (ws_size >= needed(5)) ? 5 : 4;
    const int SC = 1 << scLog2;

    char* ws = (char*)d_ws;
    unsigned short* Vt2 = (unsigned short*)ws;                       // 1 MB
    unsigned short* Wt2 = (unsigned short*)(ws + (1u << 20));        // 64 KB
    float4* sQ  = (float4*)(ws + (1u << 20) + (64u << 10));          // 128 KB
    float*  dE1 = (float*)(ws + (1u << 20) + (192u << 10));          // 32 KB
    float*  dE2 = (float*)(ws + (1u << 20) + (224u << 10));          // 32 KB
    unsigned short* maskB = (unsigned short*)(ws + (1u << 20) + (256u << 10));
    unsigned short* numPartB = (unsigned short*)(ws + HEAD);
    float*  zPart  = (float*)((char*)numPartB
                              + 2ull * SC * NTRAIN * CDIM * sizeof(unsigned short));

    hipLaunchKernelGGL(k_madj, dim3(1024), dim3(256), 0, stream,
                       adj1, adj2, idxt, W, Wt2, maskB, (float*)d_out);
    hipLaunchKernelGGL(k_wh, dim3(512), dim3(64), 0, stream,
                       feat, Wt2, av, Vt2, sQ, dE1, dE2);
    if (scLog2 == 5)
        hipLaunchKernelGGL((k_mattn<5>), dim3(32 * 32), dim3(256), 0, stream,
                           maskB, Vt2, sQ, dE1, dE2, idxt, numPartB, zPart);
    else
        hipLaunchKernelGGL((k_mattn<4>), dim3(32 * 16), dim3(256), 0, stream,
                           maskB, Vt2, sQ, dE1, dE2, idxt, numPartB, zPart);
    hipLaunchKernelGGL(k_loss, dim3(NTRAIN / 4), dim3(256), 0, stream,
                       numPartB, zPart, labels, idxt, (float*)d_out, scLog2);
}